// Round 3
// baseline (97.610 us; speedup 1.0000x reference)
//
#include <hip/hip_runtime.h>
#include <math.h>

// Problem constants
#define H 32
#define W 32
#define OH 94
#define OW 94
#define NMESH (OH * OW)   // 8836
#define B 4
#define M 4096
#define BM (B * M)        // 16384

// Mesh chunking: 32 chunks of ceil(8836/32)=277, padded to 288 (div by 16 for
// the ping-pong double-buffered inner loop).
#define NCHUNK 32
#define CH 277
#define CHPAD 288
#define BPB (NCHUNK * CHPAD)   // per-batch padded mesh entries = 9216
#define MESH_TOTAL (B * BPB)   // 36864

// Kernel 1: bilinear mesh refine -> float4(-2x, -2y, -2z, ||m||^2); zero out.
// Premultiply by -2 (exact in fp32): d_partial = fma(px,-2mx, fma(py,-2my, fma(pz,-2mz, ||m||^2))).
__global__ __launch_bounds__(256) void mesh_init_kernel(
        const float* __restrict__ nm, float4* __restrict__ mesh4,
        float* __restrict__ out) {
    int e = blockIdx.x * 256 + threadIdx.x;
    if (e == 0) out[0] = 0.0f;
    if (e >= MESH_TOTAL) return;

    int b = e / BPB;
    int r = e - b * BPB;
    int chunk = r / CHPAD;
    int k = r - chunk * CHPAD;
    int n = chunk * CH + k;
    if (k >= CH || n >= NMESH) {  // padding sentinel: never the min
        mesh4[e] = make_float4(0.f, 0.f, 0.f, 3.0e38f);
        return;
    }
    int oy = n / OW;
    int ox = n - oy * OW;
    float ys = (float)oy / 3.0f;
    float xs = (float)ox / 3.0f;
    int y0 = (int)floorf(ys); if (y0 > H - 2) y0 = H - 2;
    int x0 = (int)floorf(xs); if (x0 > W - 2) x0 = W - 2;
    float wy = ys - (float)y0;
    float wx = xs - (float)x0;

    const float* base = nm + b * 3 * H * W;
    float vals[3];
#pragma unroll
    for (int c = 0; c < 3; ++c) {
        const float* p = base + c * H * W + y0 * W + x0;
        float v00 = p[0], v01 = p[1], v10 = p[W], v11 = p[W + 1];
        float top = v00 * (1.0f - wx) + v01 * wx;
        float bot = v10 * (1.0f - wx) + v11 * wx;
        vals[c] = top * (1.0f - wy) + bot * wy;
    }
    float nrm = vals[0] * vals[0] + vals[1] * vals[1] + vals[2] * vals[2];
    mesh4[e] = make_float4(-2.0f * vals[0], -2.0f * vals[1], -2.0f * vals[2], nrm);
}

// Kernel 2: per pc point, min over one mesh chunk of (||m||^2 - 2 p.m).
// Mesh reads are wave-uniform -> scalar s_load path. Ping-pong double buffer:
// 8-point batch B loads while batch A computes, so each s_load_dwordx16 pair
// is issued ~128 cycles before its s_waitcnt.
__global__ __launch_bounds__(256) void dist_kernel(
        const float* __restrict__ pc, const float4* __restrict__ mesh4,
        float* __restrict__ minpart) {
    int b = blockIdx.z;                        // 4
    int i = blockIdx.y * 256 + threadIdx.x;    // pc point in [0, 4096)
    int chunk = blockIdx.x;                    // 32
    const float4* mp = mesh4 + b * BPB + chunk * CHPAD;

    float px = pc[(b * 3 + 0) * M + i];
    float py = pc[(b * 3 + 1) * M + i];
    float pz = pc[(b * 3 + 2) * M + i];

    float m[8];
#pragma unroll
    for (int u = 0; u < 8; ++u) m[u] = 3.0e38f;

    float4 A[8], Bb[8];
#pragma unroll
    for (int u = 0; u < 8; ++u) A[u] = mp[u];

    for (int j = 0; j < CHPAD; j += 16) {
        // load batch B (points j+8 .. j+15) while computing batch A
#pragma unroll
        for (int u = 0; u < 8; ++u) Bb[u] = mp[j + 8 + u];
#pragma unroll
        for (int u = 0; u < 8; ++u) {
            float s = fmaf(px, A[u].x, fmaf(py, A[u].y, fmaf(pz, A[u].z, A[u].w)));
            m[u] = fminf(m[u], s);
        }
        // load next batch A (points j+16 .. j+23) while computing batch B
        if (j + 16 < CHPAD) {
#pragma unroll
            for (int u = 0; u < 8; ++u) A[u] = mp[j + 16 + u];
        }
#pragma unroll
        for (int u = 0; u < 8; ++u) {
            float s = fmaf(px, Bb[u].x, fmaf(py, Bb[u].y, fmaf(pz, Bb[u].z, Bb[u].w)));
            m[u] = fminf(m[u], s);
        }
    }
    float v = fminf(fminf(fminf(m[0], m[1]), fminf(m[2], m[3])),
                    fminf(fminf(m[4], m[5]), fminf(m[6], m[7])));
    minpart[(chunk * B + b) * M + i] = v;
}

// Kernel 3: fold 32 chunk-partials, add ||p||^2, mean via block reduce + atomicAdd.
__global__ __launch_bounds__(256) void reduce_kernel(
        const float* __restrict__ pc, const float* __restrict__ minpart,
        float* __restrict__ out) {
    int e = blockIdx.x * 256 + threadIdx.x;  // [0, 16384)
    int b = e >> 12;
    int i = e & (M - 1);

    float v = 3.0e38f;
#pragma unroll
    for (int c = 0; c < NCHUNK; ++c)
        v = fminf(v, minpart[(c * B + b) * M + i]);

    float px = pc[(b * 3 + 0) * M + i];
    float py = pc[(b * 3 + 1) * M + i];
    float pz = pc[(b * 3 + 2) * M + i];
    float pn = fmaf(px, px, fmaf(py, py, pz * pz));
    float d = v + pn;

    // wave64 reduce
    for (int off = 32; off > 0; off >>= 1)
        d += __shfl_down(d, off, 64);
    __shared__ float smem[4];
    int lane = threadIdx.x & 63;
    int wid = threadIdx.x >> 6;
    if (lane == 0) smem[wid] = d;
    __syncthreads();
    if (threadIdx.x == 0) {
        float s = (smem[0] + smem[1]) + (smem[2] + smem[3]);
        atomicAdd(out, s * (1.0f / (float)BM));
    }
}

extern "C" void kernel_launch(void* const* d_in, const int* in_sizes, int n_in,
                              void* d_out, int out_size, void* d_ws, size_t ws_size,
                              hipStream_t stream) {
    const float* nm = (const float*)d_in[0];   // (4,3,32,32)
    const float* pc = (const float*)d_in[1];   // (4,3,4096)
    float* out = (float*)d_out;                // scalar

    float* minpart = (float*)d_ws;                                        // 2 MiB
    float4* mesh4 = (float4*)((char*)d_ws + (size_t)NCHUNK * BM * sizeof(float));

    int g1 = (MESH_TOTAL + 255) / 256;
    mesh_init_kernel<<<g1, 256, 0, stream>>>(nm, mesh4, out);

    dist_kernel<<<dim3(NCHUNK, M / 256, B), 256, 0, stream>>>(pc, mesh4, minpart);

    reduce_kernel<<<BM / 256, 256, 0, stream>>>(pc, minpart, out);
}